// Round 1
// baseline (435.967 us; speedup 1.0000x reference)
//
#include <hip/hip_runtime.h>
#include <hip/hip_bf16.h>
#include <math.h>

// Problem constants: T=2048, B=2, E=1024, H=16, d=64
constexpr int T_DIM = 2048;
constexpr int B_DIM = 2;
constexpr int E_DIM = 1024;
// Q pre-scale folded into in_proj epilogue: d^-0.5 * log2(e); attention then
// computes p = exp2(s_scaled) = exp(s_orig * d^-0.5).
constexpr float QK_SCALE = 0.18033688011112042f;

#if __has_builtin(__builtin_amdgcn_exp2f)
#define EXP2F(x) __builtin_amdgcn_exp2f(x)
#else
#define EXP2F(x) exp2f(x)
#endif

typedef __attribute__((ext_vector_type(8))) short short8;   // 8 x bf16 (4 VGPRs)
typedef __attribute__((ext_vector_type(4))) float f32x4;    // MFMA C/D frag

__device__ inline short f2bf(float x) {
    union { __hip_bfloat16 b; short s; } u;
    u.b = __float2bfloat16(x);
    return u.s;
}
__device__ inline float bf2f(short s) {
    union { __hip_bfloat16 b; short s; } u;
    u.s = s;
    return __bfloat162float(u.b);
}

// pack two positive f32 to bf16 pair (lo in low half), RNE-ties-away.
__device__ inline int pack_bf16(float hi, float lo) {
    union { float f; unsigned u; } a, b;
    a.f = hi; b.f = lo;
    return (int)__builtin_amdgcn_perm(a.u + 0x8000u, b.u + 0x8000u, 0x07060302u);
}

__device__ inline void gl2lds16(const void* g, void* l) {
    __builtin_amdgcn_global_load_lds(
        (const __attribute__((address_space(1))) unsigned int*)g,
        (__attribute__((address_space(3))) unsigned int*)l, 16, 0, 0);
}

__device__ inline f32x4 mfma_bf16(short8 a, short8 b, f32x4 c) {
    return __builtin_amdgcn_mfma_f32_16x16x32_bf16(a, b, c, 0, 0, 0);
}

// ---------------------------------------------------------------------------
// Fused split: query (hi only), w_in (hi+lo), w_out (hi+lo). One launch.
// ---------------------------------------------------------------------------
__global__ __launch_bounds__(256)
void split_all_kernel(const float* __restrict__ query,
                      const float* __restrict__ w_in,
                      const float* __restrict__ w_out,
                      short* __restrict__ qh,
                      short* __restrict__ wih, short* __restrict__ wil,
                      short* __restrict__ woh, short* __restrict__ wol,
                      int nq4, int nwi4, int nwo4)
{
    int i = blockIdx.x * 256 + threadIdx.x;
    const float* src; short* dh; short* dl; int k; int do_lo;
    if (i < nq4) { src = query; dh = qh; dl = nullptr; k = i; do_lo = 0; }
    else if (i < nq4 + nwi4) { src = w_in; dh = wih; dl = wil; k = i - nq4; do_lo = 1; }
    else { src = w_out; dh = woh; dl = wol; k = i - nq4 - nwi4; do_lo = 1; }
    float4 v = ((const float4*)src)[k];
    short h0 = f2bf(v.x), h1 = f2bf(v.y), h2 = f2bf(v.z), h3 = f2bf(v.w);
    ((short4*)dh)[k] = make_short4(h0, h1, h2, h3);
    if (do_lo) {
        short l0 = f2bf(v.x - bf2f(h0));
        short l1 = f2bf(v.y - bf2f(h1));
        short l2 = f2bf(v.z - bf2f(h2));
        short l3 = f2bf(v.w - bf2f(h3));
        ((short4*)dl)[k] = make_short4(l0, l1, l2, l3);
    }
}

// ---------------------------------------------------------------------------
// 128x128-tile GEMM (in_proj): C = A @ W^T + bias, 2-MFMA w-split, bf16 out,
// q-columns pre-scaled by QK_SCALE.  (verified r2-r8)
// ---------------------------------------------------------------------------
__global__ __launch_bounds__(256)
void gemm_in(const short* __restrict__ Ah,
             const short* __restrict__ Wh, const short* __restrict__ Wl,
             const float* __restrict__ bias, short* __restrict__ Cout,
             int M, int N, int K)
{
    __shared__ __align__(16) short AsH[128 * 32];
    __shared__ __align__(16) short WsH[128 * 32];
    __shared__ __align__(16) short WsL[128 * 32];

    const int tid  = threadIdx.x;
    const int lane = tid & 63;
    const int wave = tid >> 6;
    const int rm = (wave >> 1) * 64;
    const int cn = (wave & 1) * 64;
    const int m0 = blockIdx.y * 128;
    const int n0 = blockIdx.x * 128;

    const int srow0 = wave * 32 + (lane >> 2);
    const int srow1 = srow0 + 16;
    const int p4 = lane & 3;
    const int kc0 = p4 ^ ((srow0 >> 1) & 3);
    const int kc1 = p4 ^ ((srow1 >> 1) & 3);

    short* ldsA0 = &AsH[(wave * 32) * 32];
    short* ldsA1 = &AsH[(wave * 32 + 16) * 32];
    short* ldsW0 = &WsH[(wave * 32) * 32];
    short* ldsW1 = &WsH[(wave * 32 + 16) * 32];
    short* ldsWl0 = &WsL[(wave * 32) * 32];
    short* ldsWl1 = &WsL[(wave * 32 + 16) * 32];

    const size_t ga0 = (size_t)(m0 + srow0) * K + kc0 * 8;
    const size_t ga1 = (size_t)(m0 + srow1) * K + kc1 * 8;
    const size_t gw0 = (size_t)(n0 + srow0) * K + kc0 * 8;
    const size_t gw1 = (size_t)(n0 + srow1) * K + kc1 * 8;

    const f32x4 zero = {0.f, 0.f, 0.f, 0.f};
    f32x4 acc[4][4];
    #pragma unroll
    for (int i = 0; i < 4; ++i)
        #pragma unroll
        for (int j = 0; j < 4; ++j) acc[i][j] = zero;

    const int fr = lane & 15;
    const int qc = lane >> 4;

    for (int k0 = 0; k0 < K; k0 += 32) {
        if (k0) __syncthreads();
        gl2lds16(Ah + ga0 + k0, ldsA0);
        gl2lds16(Ah + ga1 + k0, ldsA1);
        gl2lds16(Wh + gw0 + k0, ldsW0);
        gl2lds16(Wh + gw1 + k0, ldsW1);
        gl2lds16(Wl + gw0 + k0, ldsWl0);
        gl2lds16(Wl + gw1 + k0, ldsWl1);
        __syncthreads();

        short8 ahf[4], bhf[4], blf[4];
        #pragma unroll
        for (int i = 0; i < 4; ++i) {
            int r = rm + 16 * i + fr;
            int slot = qc ^ ((r >> 1) & 3);
            ahf[i] = *(const short8*)&AsH[r * 32 + slot * 8];
        }
        #pragma unroll
        for (int j = 0; j < 4; ++j) {
            int r = cn + 16 * j + fr;
            int slot = qc ^ ((r >> 1) & 3);
            bhf[j] = *(const short8*)&WsH[r * 32 + slot * 8];
            blf[j] = *(const short8*)&WsL[r * 32 + slot * 8];
        }
        #pragma unroll
        for (int i = 0; i < 4; ++i)
            #pragma unroll
            for (int j = 0; j < 4; ++j) {
                acc[i][j] = mfma_bf16(ahf[i], bhf[j], acc[i][j]);
                acc[i][j] = mfma_bf16(ahf[i], blf[j], acc[i][j]);
            }
    }

    const int g = lane >> 4;
    #pragma unroll
    for (int j = 0; j < 4; ++j) {
        int col = n0 + cn + 16 * j + fr;
        float bj = bias[col];
        float cs = (((col >> 6) % 3) == 0) ? QK_SCALE : 1.0f;
        #pragma unroll
        for (int i = 0; i < 4; ++i)
            #pragma unroll
            for (int r = 0; r < 4; ++r) {
                int row = m0 + rm + 16 * i + g * 4 + r;
                Cout[(size_t)row * N + col] = f2bf((acc[i][j][r] + bj) * cs);
            }
    }
}

// ---------------------------------------------------------------------------
// 64x128-tile GEMM (out_proj): 3-MFMA full split, fp32 out. 512 blocks.
// (verified r7/r8)
// ---------------------------------------------------------------------------
__global__ __launch_bounds__(256)
void gemm_out(const short* __restrict__ Ah, const short* __restrict__ Al,
              const short* __restrict__ Wh, const short* __restrict__ Wl,
              const float* __restrict__ bias, float* __restrict__ Cout,
              int M, int N, int K)
{
    __shared__ __align__(16) short AsH[64 * 32];
    __shared__ __align__(16) short AsL[64 * 32];
    __shared__ __align__(16) short WsH[128 * 32];
    __shared__ __align__(16) short WsL[128 * 32];

    const int tid  = threadIdx.x;
    const int lane = tid & 63;
    const int wave = tid >> 6;
    const int m0 = blockIdx.y * 64;
    const int n0 = blockIdx.x * 128;

    const int arow = wave * 16 + (lane >> 2);
    const int akc = (lane & 3) ^ ((arow >> 1) & 3);
    const size_t gaA = (size_t)(m0 + arow) * K + akc * 8;
    const int wrow0 = wave * 32 + (lane >> 2);
    const int wrow1 = wrow0 + 16;
    const int wkc0 = (lane & 3) ^ ((wrow0 >> 1) & 3);
    const int wkc1 = (lane & 3) ^ ((wrow1 >> 1) & 3);
    const size_t gw0 = (size_t)(n0 + wrow0) * K + wkc0 * 8;
    const size_t gw1 = (size_t)(n0 + wrow1) * K + wkc1 * 8;

    short* ldsAh = &AsH[wave * 512];
    short* ldsAl = &AsL[wave * 512];
    short* ldsW0 = &WsH[(wave * 2) * 512];
    short* ldsW1 = &WsH[(wave * 2 + 1) * 512];
    short* ldsWl0 = &WsL[(wave * 2) * 512];
    short* ldsWl1 = &WsL[(wave * 2 + 1) * 512];

    const f32x4 zero = {0.f, 0.f, 0.f, 0.f};
    f32x4 acc[4][2];
    #pragma unroll
    for (int i = 0; i < 4; ++i) { acc[i][0] = zero; acc[i][1] = zero; }

    const int fr = lane & 15;
    const int g = lane >> 4;

    for (int k0 = 0; k0 < K; k0 += 32) {
        if (k0) __syncthreads();
        gl2lds16(Ah + gaA + k0, ldsAh);
        gl2lds16(Al + gaA + k0, ldsAl);
        gl2lds16(Wh + gw0 + k0, ldsW0);
        gl2lds16(Wh + gw1 + k0, ldsW1);
        gl2lds16(Wl + gw0 + k0, ldsWl0);
        gl2lds16(Wl + gw1 + k0, ldsWl1);
        __syncthreads();

        short8 ahf[4], alf[4], bhf[2], blf[2];
        #pragma unroll
        for (int i = 0; i < 4; ++i) {
            int r = 16 * i + fr;
            int slot = g ^ ((r >> 1) & 3);
            ahf[i] = *(const short8*)&AsH[r * 32 + slot * 8];
            alf[i] = *(const short8*)&AsL[r * 32 + slot * 8];
        }
        #pragma unroll
        for (int j = 0; j < 2; ++j) {
            int r = wave * 32 + 16 * j + fr;
            int slot = g ^ ((r >> 1) & 3);
            bhf[j] = *(const short8*)&WsH[r * 32 + slot * 8];
            blf[j] = *(const short8*)&WsL[r * 32 + slot * 8];
        }
        #pragma unroll
        for (int i = 0; i < 4; ++i)
            #pragma unroll
            for (int j = 0; j < 2; ++j) {
                acc[i][j] = mfma_bf16(ahf[i], bhf[j], acc[i][j]);
                acc[i][j] = mfma_bf16(ahf[i], blf[j], acc[i][j]);
                acc[i][j] = mfma_bf16(alf[i], bhf[j], acc[i][j]);
            }
    }

    #pragma unroll
    for (int j = 0; j < 2; ++j) {
        int col = n0 + wave * 32 + 16 * j + fr;
        float bj = bias[col];
        #pragma unroll
        for (int i = 0; i < 4; ++i)
            #pragma unroll
            for (int r = 0; r < 4; ++r) {
                int row = m0 + 16 * i + g * 4 + r;
                Cout[(size_t)row * N + col] = acc[i][j][r] + bj;
            }
    }
}

// ---------------------------------------------------------------------------
// One-shot V transpose: qkv [t][b][h*192+128+dd] -> vtp [bh][dd][t].
// (verified r5-r8)
// ---------------------------------------------------------------------------
__global__ __launch_bounds__(256)
void repack_vt(const short* __restrict__ qkv, short* __restrict__ vtp)
{
    __shared__ __align__(16) short Vl[64 * 72];

    const int tid = threadIdx.x;
    const int t0 = blockIdx.x * 64;
    const int bh = blockIdx.y;
    const int b = bh >> 4, h = bh & 15;
    const int wv = tid >> 6;
    const int m  = tid & 63;

    const short* src = qkv + ((size_t)(t0 + m) * 2 + b) * 3072 + h * 192 + 128;
    short8 v0 = *(const short8*)(src + (2 * wv) * 8);
    short8 v1 = *(const short8*)(src + (2 * wv + 1) * 8);
    #pragma unroll
    for (int j = 0; j < 8; ++j) {
        Vl[(wv * 16 + j) * 72 + m]     = v0[j];
        Vl[(wv * 16 + 8 + j) * 72 + m] = v1[j];
    }
    __syncthreads();

    const int dd = tid >> 2;
    const int oc = tid & 3;
    uint4 w0 = *(const uint4*)&Vl[dd * 72 + oc * 16];
    uint4 w1 = *(const uint4*)&Vl[dd * 72 + oc * 16 + 8];
    short* dst = vtp + (size_t)bh * (64 * 2048) + (size_t)dd * 2048 + t0 + oc * 16;
    *(uint4*)(dst) = w0;
    *(uint4*)(dst + 8) = w1;
}

// ---------------------------------------------------------------------------
// One-shot K repack into MFMA-fragment order with key permutation baked in.
// (verified r8)
// ---------------------------------------------------------------------------
__global__ __launch_bounds__(256)
void repack_kf(const short* __restrict__ qkv, short* __restrict__ kp)
{
    __shared__ __align__(16) short Kl[64 * 72];

    const int tid = threadIdx.x;
    const int t0 = blockIdx.x * 64;
    const int bh = blockIdx.y;
    const int b = bh >> 4, h = bh & 15;

    #pragma unroll
    for (int rr = 0; rr < 2; ++rr) {
        int c = tid + 256 * rr;
        int m = c >> 3, c8 = c & 7;
        *(uint4*)&Kl[m * 72 + c8 * 8] =
            *(const uint4*)(qkv + ((size_t)(t0 + m) * 2 + b) * 3072 + h * 192 + 64 + c8 * 8);
    }
    __syncthreads();

    short* dst = kp + (size_t)bh * 131072 + (size_t)blockIdx.x * 4096;
    #pragma unroll
    for (int rr = 0; rr < 2; ++rr) {
        int c = tid + 256 * rr;
        int f = c >> 6;
        int l = c & 63;
        int s = f >> 1, hh = f & 1;
        int g = l >> 4, fr = l & 15;
        int R = 16 * s + fr;
        int kk = (R & 32) | ((R & 12) << 1) | ((R & 16) >> 2) | (R & 3);
        uint4 v = *(const uint4*)&Kl[kk * 72 + hh * 32 + g * 8];
        *(uint4*)(dst + c * 8) = v;
    }
}

// ---------------------------------------------------------------------------
// Flash attention v10 — key-split occupancy doubling.
// r9 theory: v9 (2 waves/SIMD) was latency-bound: MfmaUtil 18%, VALUBusy 21%,
// Occupancy 19%, HBM 4% — both pipes idle, stalls dominate. VGPR=104 allows
// 4 waves/SIMD; only the grid (1024 blk x 2 waves) capped occupancy.
// Now: 256 threads = 4 waves/block; waves {0,1} take keys [0,1024),
// waves {2,3} keys [1024,2048) for the SAME 64 q-rows. No running max is
// tracked (plain exp2 accumulation), so the combine is linear:
// o = o0+o1, l = l0+l1 — one LDS pass at the epilogue (stride-68 pad,
// 2-way conflicts = free). Total MFMA/exp2 work, L2 and HBM traffic
// unchanged; wave-parallelism doubles.
// ---------------------------------------------------------------------------
__global__ __launch_bounds__(256, 4)
void attn_mfma(const short* __restrict__ qkv, const short* __restrict__ kp,
               const short* __restrict__ vtp,
               short* __restrict__ ctxh, short* __restrict__ ctxl)
{
    __shared__ __align__(16) float oshare[2][32 * 68];  // [qhalf][row*68+col]
    __shared__ float lshare[2][32];

    const int tid  = threadIdx.x;
    const int lane = tid & 63;
    const int wave = tid >> 6;      // 0..3
    const int qhalf = wave & 1;     // which 32 q-rows
    const int khalf = wave >> 1;    // which 1024 keys
    const int fr = lane & 15;
    const int g  = lane >> 4;

    // XCD-aware decode: 8 groups x 4 bh x 32 q-tiles(64 rows)
    const int id   = blockIdx.x;
    const int slot = id >> 3;
    const int bh   = (id & 7) * 4 + (slot & 3);
    const int q0   = (slot >> 2) * 64;
    const int b = bh >> 4, h = bh & 15;

    // ---- Q fragments: 2 sets of 16 rows (pre-scaled by QK_SCALE) ----
    short8 aq[2][2];
    #pragma unroll
    for (int set = 0; set < 2; ++set) {
        const short* qrow = qkv +
            ((size_t)(q0 + qhalf * 32 + set * 16 + fr) * 2 + b) * 3072 + h * 192;
        aq[set][0] = *(const short8*)(qrow + g * 8);
        aq[set][1] = *(const short8*)(qrow + 32 + g * 8);
    }

    const short* kb = kp + (size_t)bh * 131072 + lane * 8;
    const short* vb = vtp + (size_t)bh * 131072;
    int voff[4];
    #pragma unroll
    for (int jd = 0; jd < 4; ++jd) voff[jd] = (16 * jd + fr) * 2048 + g * 8;

    short8 ONES;
    #pragma unroll
    for (int i = 0; i < 8; ++i) ONES[i] = (short)0x3F80;  // bf16 1.0

    const f32x4 zero = {0.f, 0.f, 0.f, 0.f};
    f32x4 o[2][4];
    #pragma unroll
    for (int set = 0; set < 2; ++set)
        #pragma unroll
        for (int jd = 0; jd < 4; ++jd) o[set][jd] = zero;
    f32x4 lacc[2] = {zero, zero};

    // load tile `it` into register buffers (16 b128 loads, no waits here)
    auto load_tile = [&](int it, short8* bk, short8* bv) {
        const short* kf = kb + it * 4096;
        #pragma unroll
        for (int f = 0; f < 8; ++f) bk[f] = *(const short8*)(kf + f * 512);
        #pragma unroll
        for (int jd = 0; jd < 4; ++jd) {
            const short* vr = vb + voff[jd] + it * 64;
            bv[2 * jd]     = *(const short8*)vr;
            bv[2 * jd + 1] = *(const short8*)(vr + 32);
        }
    };

    // compute one 64-key tile from register buffers
    auto compute_tile = [&](const short8* bk, const short8* bv) {
        int afw[2][2][4];
        #pragma unroll
        for (int s = 0; s < 4; ++s)
            #pragma unroll
            for (int set = 0; set < 2; ++set) {
                f32x4 a = zero;
                a = mfma_bf16(bk[2 * s], aq[set][0], a);
                a = mfma_bf16(bk[2 * s + 1], aq[set][1], a);
                float e0 = EXP2F(a[0]), e1 = EXP2F(a[1]);
                float e2 = EXP2F(a[2]), e3 = EXP2F(a[3]);
                afw[set][s >> 1][(s & 1) * 2]     = pack_bf16(e1, e0);
                afw[set][s >> 1][(s & 1) * 2 + 1] = pack_bf16(e3, e2);
            }
        #pragma unroll
        for (int set = 0; set < 2; ++set) {
            union { int w[4]; short8 v; } A0, A1;
            #pragma unroll
            for (int w = 0; w < 4; ++w) { A0.w[w] = afw[set][0][w]; A1.w[w] = afw[set][1][w]; }
            lacc[set] = mfma_bf16(A0.v, ONES, lacc[set]);
            lacc[set] = mfma_bf16(A1.v, ONES, lacc[set]);
            #pragma unroll
            for (int jd = 0; jd < 4; ++jd) {
                o[set][jd] = mfma_bf16(A0.v, bv[2 * jd], o[set][jd]);
                o[set][jd] = mfma_bf16(A1.v, bv[2 * jd + 1], o[set][jd]);
            }
        }
    };

    short8 bkA[8], bvA[8], bkB[8], bvB[8];
    const int itBeg = khalf * 16;
    const int itEnd = itBeg + 16;
    load_tile(itBeg, bkA, bvA);
    #pragma unroll 1
    for (int it = itBeg; it < itEnd; it += 2) {
        load_tile(it + 1, bkB, bvB);          // in flight during compute A
        compute_tile(bkA, bvA);
        if (it + 2 < itEnd) load_tile(it + 2, bkA, bvA);  // in flight during B
        compute_tile(bkB, bvB);
    }

    // ---- combine key halves via LDS, then normalize, split, store ----
    if (khalf == 0) {
        #pragma unroll
        for (int set = 0; set < 2; ++set) {
            #pragma unroll
            for (int r = 0; r < 4; ++r) {
                int row = set * 16 + 4 * g + r;
                #pragma unroll
                for (int jd = 0; jd < 4; ++jd)
                    oshare[qhalf][row * 68 + 16 * jd + fr] = o[set][jd][r];
                if (fr == 0) lshare[qhalf][row] = lacc[set][r];
            }
        }
    }
    __syncthreads();
    if (khalf == 1) {
        #pragma unroll
        for (int set = 0; set < 2; ++set)
            #pragma unroll
            for (int r = 0; r < 4; ++r) {
                int row = set * 16 + 4 * g + r;
                float lt = lacc[set][r] + lshare[qhalf][row];
                float inv = 1.f / lt;
                int t = q0 + qhalf * 32 + row;
                size_t base = ((size_t)t * B_DIM + b) * E_DIM + h * 64;
                #pragma unroll
                for (int jd = 0; jd < 4; ++jd) {
                    float v = (o[set][jd][r] + oshare[qhalf][row * 68 + 16 * jd + fr]) * inv;
                    short hs = f2bf(v);
                    short ls = f2bf(v - bf2f(hs));
                    ctxh[base + 16 * jd + fr] = hs;
                    ctxl[base + 16 * jd + fr] = ls;
                }
            }
    }
}

// ---------------------------------------------------------------------------
extern "C" void kernel_launch(void* const* d_in, const int* in_sizes, int n_in,
                              void* d_out, int out_size, void* d_ws, size_t ws_size,
                              hipStream_t stream)
{
    const float* query = (const float*)d_in[0];
    const float* w_in  = (const float*)d_in[1];
    const float* b_in  = (const float*)d_in[2];
    const float* w_out = (const float*)d_in[3];
    const float* b_out = (const float*)d_in[4];
    float* out = (float*)d_out;

    char* ws = (char*)d_ws;
    short* qkv  = (short*)(ws);                  // 25.2 MB
    short* qh   = (short*)(ws + 25165824);       // 8.4 MB
    short* wih  = (short*)(ws + 33554432);       // 6.3 MB
    short* wil  = (short*)(ws + 39845888);       // 6.3 MB
    short* woh  = (short*)(ws + 46137344);       // 2.1 MB
    short* wol  = (short*)(ws + 48234496);       // 2.1 MB
    short* vtp  = (short*)(ws + 50331648);       // 8.4 MB  V^T [bh][d][t]
    short* kp   = (short*)(ws + 58720256);       // 8.4 MB  K frag-order
    short* ctxh = (short*)(ws + 25165824);       // alias qh  (dead after in_proj)
    short* ctxl = (short*)(ws + 33554432);       // alias wih (dead after in_proj)

    const int M = T_DIM * B_DIM;  // 4096

    int nq4  = (M * E_DIM) / 4;
    int nwi4 = (3 * E_DIM * E_DIM) / 4;
    int nwo4 = (E_DIM * E_DIM) / 4;
    split_all_kernel<<<(nq4 + nwi4 + nwo4) / 256, 256, 0, stream>>>(
        query, w_in, w_out, qh, wih, wil, woh, wol, nq4, nwi4, nwo4);

    // in_proj: qkv_bf16 = q @ w_in^T + b_in (w-split, 2 MFMA), q-cols pre-scaled
    gemm_in<<<dim3(3 * E_DIM / 128, M / 128), 256, 0, stream>>>(
        qh, wih, wil, b_in, qkv, M, 3 * E_DIM, E_DIM);

    // one-shot repacks: V -> [bh][d][t], K -> fragment order
    repack_vt<<<dim3(T_DIM / 64, 32), 256, 0, stream>>>(qkv, vtp);
    repack_kf<<<dim3(T_DIM / 64, 32), 256, 0, stream>>>(qkv, kp);

    // attention: 1024 blocks x 256 threads (4 waves: 2 q-halves x 2 key-halves)
    attn_mfma<<<dim3(1024), 256, 0, stream>>>(qkv, kp, vtp, ctxh, ctxl);

    // out_proj: 64x128 tiles -> 512 blocks, full split, 3 MFMA
    gemm_out<<<dim3(E_DIM / 128, M / 64), 256, 0, stream>>>(
        ctxh, ctxl, woh, wol, b_out, out, M, E_DIM, E_DIM);
}

// Round 2
// 257.031 us; speedup vs baseline: 1.6962x; 1.6962x over previous
//
#include <hip/hip_runtime.h>
#include <hip/hip_bf16.h>
#include <math.h>

// Problem constants: T=2048, B=2, E=1024, H=16, d=64
constexpr int T_DIM = 2048;
constexpr int B_DIM = 2;
constexpr int E_DIM = 1024;
// Q pre-scale folded into in_proj epilogue: d^-0.5 * log2(e); attention then
// computes p = exp2(s_scaled) = exp(s_orig * d^-0.5).
constexpr float QK_SCALE = 0.18033688011112042f;

#if __has_builtin(__builtin_amdgcn_exp2f)
#define EXP2F(x) __builtin_amdgcn_exp2f(x)
#else
#define EXP2F(x) exp2f(x)
#endif

typedef __attribute__((ext_vector_type(8))) short short8;   // 8 x bf16 (4 VGPRs)
typedef __attribute__((ext_vector_type(4))) float f32x4;    // MFMA C/D frag

__device__ inline short f2bf(float x) {
    union { __hip_bfloat16 b; short s; } u;
    u.b = __float2bfloat16(x);
    return u.s;
}
__device__ inline float bf2f(short s) {
    union { __hip_bfloat16 b; short s; } u;
    u.s = s;
    return __bfloat162float(u.b);
}

// pack two positive f32 to bf16 pair (lo in low half), RNE-ties-away.
__device__ inline int pack_bf16(float hi, float lo) {
    union { float f; unsigned u; } a, b;
    a.f = hi; b.f = lo;
    return (int)__builtin_amdgcn_perm(a.u + 0x8000u, b.u + 0x8000u, 0x07060302u);
}

__device__ inline void gl2lds16(const void* g, void* l) {
    __builtin_amdgcn_global_load_lds(
        (const __attribute__((address_space(1))) unsigned int*)g,
        (__attribute__((address_space(3))) unsigned int*)l, 16, 0, 0);
}

__device__ inline f32x4 mfma_bf16(short8 a, short8 b, f32x4 c) {
    return __builtin_amdgcn_mfma_f32_16x16x32_bf16(a, b, c, 0, 0, 0);
}

// ---------------------------------------------------------------------------
// Fused split: query (hi only), w_in (hi+lo), w_out (hi+lo). One launch.
// ---------------------------------------------------------------------------
__global__ __launch_bounds__(256)
void split_all_kernel(const float* __restrict__ query,
                      const float* __restrict__ w_in,
                      const float* __restrict__ w_out,
                      short* __restrict__ qh,
                      short* __restrict__ wih, short* __restrict__ wil,
                      short* __restrict__ woh, short* __restrict__ wol,
                      int nq4, int nwi4, int nwo4)
{
    int i = blockIdx.x * 256 + threadIdx.x;
    const float* src; short* dh; short* dl; int k; int do_lo;
    if (i < nq4) { src = query; dh = qh; dl = nullptr; k = i; do_lo = 0; }
    else if (i < nq4 + nwi4) { src = w_in; dh = wih; dl = wil; k = i - nq4; do_lo = 1; }
    else { src = w_out; dh = woh; dl = wol; k = i - nq4 - nwi4; do_lo = 1; }
    float4 v = ((const float4*)src)[k];
    short h0 = f2bf(v.x), h1 = f2bf(v.y), h2 = f2bf(v.z), h3 = f2bf(v.w);
    ((short4*)dh)[k] = make_short4(h0, h1, h2, h3);
    if (do_lo) {
        short l0 = f2bf(v.x - bf2f(h0));
        short l1 = f2bf(v.y - bf2f(h1));
        short l2 = f2bf(v.z - bf2f(h2));
        short l3 = f2bf(v.w - bf2f(h3));
        ((short4*)dl)[k] = make_short4(l0, l1, l2, l3);
    }
}

// ---------------------------------------------------------------------------
// 128x128-tile GEMM (in_proj): C = A @ W^T + bias, 2-MFMA w-split, bf16 out,
// q-columns pre-scaled by QK_SCALE.  (verified r2-r8)
// ---------------------------------------------------------------------------
__global__ __launch_bounds__(256)
void gemm_in(const short* __restrict__ Ah,
             const short* __restrict__ Wh, const short* __restrict__ Wl,
             const float* __restrict__ bias, short* __restrict__ Cout,
             int M, int N, int K)
{
    __shared__ __align__(16) short AsH[128 * 32];
    __shared__ __align__(16) short WsH[128 * 32];
    __shared__ __align__(16) short WsL[128 * 32];

    const int tid  = threadIdx.x;
    const int lane = tid & 63;
    const int wave = tid >> 6;
    const int rm = (wave >> 1) * 64;
    const int cn = (wave & 1) * 64;
    const int m0 = blockIdx.y * 128;
    const int n0 = blockIdx.x * 128;

    const int srow0 = wave * 32 + (lane >> 2);
    const int srow1 = srow0 + 16;
    const int p4 = lane & 3;
    const int kc0 = p4 ^ ((srow0 >> 1) & 3);
    const int kc1 = p4 ^ ((srow1 >> 1) & 3);

    short* ldsA0 = &AsH[(wave * 32) * 32];
    short* ldsA1 = &AsH[(wave * 32 + 16) * 32];
    short* ldsW0 = &WsH[(wave * 32) * 32];
    short* ldsW1 = &WsH[(wave * 32 + 16) * 32];
    short* ldsWl0 = &WsL[(wave * 32) * 32];
    short* ldsWl1 = &WsL[(wave * 32 + 16) * 32];

    const size_t ga0 = (size_t)(m0 + srow0) * K + kc0 * 8;
    const size_t ga1 = (size_t)(m0 + srow1) * K + kc1 * 8;
    const size_t gw0 = (size_t)(n0 + srow0) * K + kc0 * 8;
    const size_t gw1 = (size_t)(n0 + srow1) * K + kc1 * 8;

    const f32x4 zero = {0.f, 0.f, 0.f, 0.f};
    f32x4 acc[4][4];
    #pragma unroll
    for (int i = 0; i < 4; ++i)
        #pragma unroll
        for (int j = 0; j < 4; ++j) acc[i][j] = zero;

    const int fr = lane & 15;
    const int qc = lane >> 4;

    for (int k0 = 0; k0 < K; k0 += 32) {
        if (k0) __syncthreads();
        gl2lds16(Ah + ga0 + k0, ldsA0);
        gl2lds16(Ah + ga1 + k0, ldsA1);
        gl2lds16(Wh + gw0 + k0, ldsW0);
        gl2lds16(Wh + gw1 + k0, ldsW1);
        gl2lds16(Wl + gw0 + k0, ldsWl0);
        gl2lds16(Wl + gw1 + k0, ldsWl1);
        __syncthreads();

        short8 ahf[4], bhf[4], blf[4];
        #pragma unroll
        for (int i = 0; i < 4; ++i) {
            int r = rm + 16 * i + fr;
            int slot = qc ^ ((r >> 1) & 3);
            ahf[i] = *(const short8*)&AsH[r * 32 + slot * 8];
        }
        #pragma unroll
        for (int j = 0; j < 4; ++j) {
            int r = cn + 16 * j + fr;
            int slot = qc ^ ((r >> 1) & 3);
            bhf[j] = *(const short8*)&WsH[r * 32 + slot * 8];
            blf[j] = *(const short8*)&WsL[r * 32 + slot * 8];
        }
        #pragma unroll
        for (int i = 0; i < 4; ++i)
            #pragma unroll
            for (int j = 0; j < 4; ++j) {
                acc[i][j] = mfma_bf16(ahf[i], bhf[j], acc[i][j]);
                acc[i][j] = mfma_bf16(ahf[i], blf[j], acc[i][j]);
            }
    }

    const int g = lane >> 4;
    #pragma unroll
    for (int j = 0; j < 4; ++j) {
        int col = n0 + cn + 16 * j + fr;
        float bj = bias[col];
        float cs = (((col >> 6) % 3) == 0) ? QK_SCALE : 1.0f;
        #pragma unroll
        for (int i = 0; i < 4; ++i)
            #pragma unroll
            for (int r = 0; r < 4; ++r) {
                int row = m0 + rm + 16 * i + g * 4 + r;
                Cout[(size_t)row * N + col] = f2bf((acc[i][j][r] + bj) * cs);
            }
    }
}

// ---------------------------------------------------------------------------
// 64x128-tile GEMM (out_proj): 3-MFMA full split, fp32 out. 512 blocks.
// (verified r7/r8)
// ---------------------------------------------------------------------------
__global__ __launch_bounds__(256)
void gemm_out(const short* __restrict__ Ah, const short* __restrict__ Al,
              const short* __restrict__ Wh, const short* __restrict__ Wl,
              const float* __restrict__ bias, float* __restrict__ Cout,
              int M, int N, int K)
{
    __shared__ __align__(16) short AsH[64 * 32];
    __shared__ __align__(16) short AsL[64 * 32];
    __shared__ __align__(16) short WsH[128 * 32];
    __shared__ __align__(16) short WsL[128 * 32];

    const int tid  = threadIdx.x;
    const int lane = tid & 63;
    const int wave = tid >> 6;
    const int m0 = blockIdx.y * 64;
    const int n0 = blockIdx.x * 128;

    const int arow = wave * 16 + (lane >> 2);
    const int akc = (lane & 3) ^ ((arow >> 1) & 3);
    const size_t gaA = (size_t)(m0 + arow) * K + akc * 8;
    const int wrow0 = wave * 32 + (lane >> 2);
    const int wrow1 = wrow0 + 16;
    const int wkc0 = (lane & 3) ^ ((wrow0 >> 1) & 3);
    const int wkc1 = (lane & 3) ^ ((wrow1 >> 1) & 3);
    const size_t gw0 = (size_t)(n0 + wrow0) * K + wkc0 * 8;
    const size_t gw1 = (size_t)(n0 + wrow1) * K + wkc1 * 8;

    short* ldsAh = &AsH[wave * 512];
    short* ldsAl = &AsL[wave * 512];
    short* ldsW0 = &WsH[(wave * 2) * 512];
    short* ldsW1 = &WsH[(wave * 2 + 1) * 512];
    short* ldsWl0 = &WsL[(wave * 2) * 512];
    short* ldsWl1 = &WsL[(wave * 2 + 1) * 512];

    const f32x4 zero = {0.f, 0.f, 0.f, 0.f};
    f32x4 acc[4][2];
    #pragma unroll
    for (int i = 0; i < 4; ++i) { acc[i][0] = zero; acc[i][1] = zero; }

    const int fr = lane & 15;
    const int g = lane >> 4;

    for (int k0 = 0; k0 < K; k0 += 32) {
        if (k0) __syncthreads();
        gl2lds16(Ah + gaA + k0, ldsAh);
        gl2lds16(Al + gaA + k0, ldsAl);
        gl2lds16(Wh + gw0 + k0, ldsW0);
        gl2lds16(Wh + gw1 + k0, ldsW1);
        gl2lds16(Wl + gw0 + k0, ldsWl0);
        gl2lds16(Wl + gw1 + k0, ldsWl1);
        __syncthreads();

        short8 ahf[4], alf[4], bhf[2], blf[2];
        #pragma unroll
        for (int i = 0; i < 4; ++i) {
            int r = 16 * i + fr;
            int slot = g ^ ((r >> 1) & 3);
            ahf[i] = *(const short8*)&AsH[r * 32 + slot * 8];
            alf[i] = *(const short8*)&AsL[r * 32 + slot * 8];
        }
        #pragma unroll
        for (int j = 0; j < 2; ++j) {
            int r = wave * 32 + 16 * j + fr;
            int slot = g ^ ((r >> 1) & 3);
            bhf[j] = *(const short8*)&WsH[r * 32 + slot * 8];
            blf[j] = *(const short8*)&WsL[r * 32 + slot * 8];
        }
        #pragma unroll
        for (int i = 0; i < 4; ++i)
            #pragma unroll
            for (int j = 0; j < 2; ++j) {
                acc[i][j] = mfma_bf16(ahf[i], bhf[j], acc[i][j]);
                acc[i][j] = mfma_bf16(ahf[i], blf[j], acc[i][j]);
                acc[i][j] = mfma_bf16(alf[i], bhf[j], acc[i][j]);
            }
    }

    #pragma unroll
    for (int j = 0; j < 2; ++j) {
        int col = n0 + wave * 32 + 16 * j + fr;
        float bj = bias[col];
        #pragma unroll
        for (int i = 0; i < 4; ++i)
            #pragma unroll
            for (int r = 0; r < 4; ++r) {
                int row = m0 + 16 * i + g * 4 + r;
                Cout[(size_t)row * N + col] = acc[i][j][r] + bj;
            }
    }
}

// ---------------------------------------------------------------------------
// One-shot V transpose: qkv [t][b][h*192+128+dd] -> vtp [bh][dd][t].
// (verified r5-r8)
// ---------------------------------------------------------------------------
__global__ __launch_bounds__(256)
void repack_vt(const short* __restrict__ qkv, short* __restrict__ vtp)
{
    __shared__ __align__(16) short Vl[64 * 72];

    const int tid = threadIdx.x;
    const int t0 = blockIdx.x * 64;
    const int bh = blockIdx.y;
    const int b = bh >> 4, h = bh & 15;
    const int wv = tid >> 6;
    const int m  = tid & 63;

    const short* src = qkv + ((size_t)(t0 + m) * 2 + b) * 3072 + h * 192 + 128;
    short8 v0 = *(const short8*)(src + (2 * wv) * 8);
    short8 v1 = *(const short8*)(src + (2 * wv + 1) * 8);
    #pragma unroll
    for (int j = 0; j < 8; ++j) {
        Vl[(wv * 16 + j) * 72 + m]     = v0[j];
        Vl[(wv * 16 + 8 + j) * 72 + m] = v1[j];
    }
    __syncthreads();

    const int dd = tid >> 2;
    const int oc = tid & 3;
    uint4 w0 = *(const uint4*)&Vl[dd * 72 + oc * 16];
    uint4 w1 = *(const uint4*)&Vl[dd * 72 + oc * 16 + 8];
    short* dst = vtp + (size_t)bh * (64 * 2048) + (size_t)dd * 2048 + t0 + oc * 16;
    *(uint4*)(dst) = w0;
    *(uint4*)(dst + 8) = w1;
}

// ---------------------------------------------------------------------------
// One-shot K repack into MFMA-fragment order with key permutation baked in.
// (verified r8)
// ---------------------------------------------------------------------------
__global__ __launch_bounds__(256)
void repack_kf(const short* __restrict__ qkv, short* __restrict__ kp)
{
    __shared__ __align__(16) short Kl[64 * 72];

    const int tid = threadIdx.x;
    const int t0 = blockIdx.x * 64;
    const int bh = blockIdx.y;
    const int b = bh >> 4, h = bh & 15;

    #pragma unroll
    for (int rr = 0; rr < 2; ++rr) {
        int c = tid + 256 * rr;
        int m = c >> 3, c8 = c & 7;
        *(uint4*)&Kl[m * 72 + c8 * 8] =
            *(const uint4*)(qkv + ((size_t)(t0 + m) * 2 + b) * 3072 + h * 192 + 64 + c8 * 8);
    }
    __syncthreads();

    short* dst = kp + (size_t)bh * 131072 + (size_t)blockIdx.x * 4096;
    #pragma unroll
    for (int rr = 0; rr < 2; ++rr) {
        int c = tid + 256 * rr;
        int f = c >> 6;
        int l = c & 63;
        int s = f >> 1, hh = f & 1;
        int g = l >> 4, fr = l & 15;
        int R = 16 * s + fr;
        int kk = (R & 32) | ((R & 12) << 1) | ((R & 16) >> 2) | (R & 3);
        uint4 v = *(const uint4*)&Kl[kk * 72 + hh * 32 + g * 8];
        *(uint4*)(dst + c * 8) = v;
    }
}

// ---------------------------------------------------------------------------
// Flash attention v11 — key-split occupancy doubling, spill fixed.
// r9 post-mortem: __launch_bounds__(256,4) capped VGPR at 64 -> the dbuf
// register tiles spilled to scratch (WRITE_SIZE 729 MB/dispatch, 3x slower).
// r10: identical structure, __launch_bounds__(256,2) -> VGPR cap 256;
// expected allocation ~104 (same per-thread code as v9) which naturally
// yields 4 waves/SIMD (2048-unit pool / 104 -> 16 waves/CU). Waves {0,1}
// take keys [0,1024), waves {2,3} keys [1024,2048) for the same 64 q-rows;
// linear combine (no running max) through 17.4 KB LDS at epilogue.
// ---------------------------------------------------------------------------
__global__ __launch_bounds__(256, 2)
void attn_mfma(const short* __restrict__ qkv, const short* __restrict__ kp,
               const short* __restrict__ vtp,
               short* __restrict__ ctxh, short* __restrict__ ctxl)
{
    __shared__ __align__(16) float oshare[2][32 * 68];  // [qhalf][row*68+col]
    __shared__ float lshare[2][32];

    const int tid  = threadIdx.x;
    const int lane = tid & 63;
    const int wave = tid >> 6;      // 0..3
    const int qhalf = wave & 1;     // which 32 q-rows
    const int khalf = wave >> 1;    // which 1024 keys
    const int fr = lane & 15;
    const int g  = lane >> 4;

    // XCD-aware decode: 8 groups x 4 bh x 32 q-tiles(64 rows)
    const int id   = blockIdx.x;
    const int slot = id >> 3;
    const int bh   = (id & 7) * 4 + (slot & 3);
    const int q0   = (slot >> 2) * 64;
    const int b = bh >> 4, h = bh & 15;

    // ---- Q fragments: 2 sets of 16 rows (pre-scaled by QK_SCALE) ----
    short8 aq[2][2];
    #pragma unroll
    for (int set = 0; set < 2; ++set) {
        const short* qrow = qkv +
            ((size_t)(q0 + qhalf * 32 + set * 16 + fr) * 2 + b) * 3072 + h * 192;
        aq[set][0] = *(const short8*)(qrow + g * 8);
        aq[set][1] = *(const short8*)(qrow + 32 + g * 8);
    }

    const short* kb = kp + (size_t)bh * 131072 + lane * 8;
    const short* vb = vtp + (size_t)bh * 131072;
    int voff[4];
    #pragma unroll
    for (int jd = 0; jd < 4; ++jd) voff[jd] = (16 * jd + fr) * 2048 + g * 8;

    short8 ONES;
    #pragma unroll
    for (int i = 0; i < 8; ++i) ONES[i] = (short)0x3F80;  // bf16 1.0

    const f32x4 zero = {0.f, 0.f, 0.f, 0.f};
    f32x4 o[2][4];
    #pragma unroll
    for (int set = 0; set < 2; ++set)
        #pragma unroll
        for (int jd = 0; jd < 4; ++jd) o[set][jd] = zero;
    f32x4 lacc[2] = {zero, zero};

    // load tile `it` into register buffers (16 b128 loads, no waits here)
    auto load_tile = [&](int it, short8* bk, short8* bv) {
        const short* kf = kb + it * 4096;
        #pragma unroll
        for (int f = 0; f < 8; ++f) bk[f] = *(const short8*)(kf + f * 512);
        #pragma unroll
        for (int jd = 0; jd < 4; ++jd) {
            const short* vr = vb + voff[jd] + it * 64;
            bv[2 * jd]     = *(const short8*)vr;
            bv[2 * jd + 1] = *(const short8*)(vr + 32);
        }
    };

    // compute one 64-key tile from register buffers
    auto compute_tile = [&](const short8* bk, const short8* bv) {
        int afw[2][2][4];
        #pragma unroll
        for (int s = 0; s < 4; ++s)
            #pragma unroll
            for (int set = 0; set < 2; ++set) {
                f32x4 a = zero;
                a = mfma_bf16(bk[2 * s], aq[set][0], a);
                a = mfma_bf16(bk[2 * s + 1], aq[set][1], a);
                float e0 = EXP2F(a[0]), e1 = EXP2F(a[1]);
                float e2 = EXP2F(a[2]), e3 = EXP2F(a[3]);
                afw[set][s >> 1][(s & 1) * 2]     = pack_bf16(e1, e0);
                afw[set][s >> 1][(s & 1) * 2 + 1] = pack_bf16(e3, e2);
            }
        #pragma unroll
        for (int set = 0; set < 2; ++set) {
            union { int w[4]; short8 v; } A0, A1;
            #pragma unroll
            for (int w = 0; w < 4; ++w) { A0.w[w] = afw[set][0][w]; A1.w[w] = afw[set][1][w]; }
            lacc[set] = mfma_bf16(A0.v, ONES, lacc[set]);
            lacc[set] = mfma_bf16(A1.v, ONES, lacc[set]);
            #pragma unroll
            for (int jd = 0; jd < 4; ++jd) {
                o[set][jd] = mfma_bf16(A0.v, bv[2 * jd], o[set][jd]);
                o[set][jd] = mfma_bf16(A1.v, bv[2 * jd + 1], o[set][jd]);
            }
        }
    };

    short8 bkA[8], bvA[8], bkB[8], bvB[8];
    const int itBeg = khalf * 16;
    const int itEnd = itBeg + 16;
    load_tile(itBeg, bkA, bvA);
    #pragma unroll 1
    for (int it = itBeg; it < itEnd; it += 2) {
        load_tile(it + 1, bkB, bvB);          // in flight during compute A
        compute_tile(bkA, bvA);
        if (it + 2 < itEnd) load_tile(it + 2, bkA, bvA);  // in flight during B
        compute_tile(bkB, bvB);
    }

    // ---- combine key halves via LDS, then normalize, split, store ----
    if (khalf == 0) {
        #pragma unroll
        for (int set = 0; set < 2; ++set) {
            #pragma unroll
            for (int r = 0; r < 4; ++r) {
                int row = set * 16 + 4 * g + r;
                #pragma unroll
                for (int jd = 0; jd < 4; ++jd)
                    oshare[qhalf][row * 68 + 16 * jd + fr] = o[set][jd][r];
                if (fr == 0) lshare[qhalf][row] = lacc[set][r];
            }
        }
    }
    __syncthreads();
    if (khalf == 1) {
        #pragma unroll
        for (int set = 0; set < 2; ++set)
            #pragma unroll
            for (int r = 0; r < 4; ++r) {
                int row = set * 16 + 4 * g + r;
                float lt = lacc[set][r] + lshare[qhalf][row];
                float inv = 1.f / lt;
                int t = q0 + qhalf * 32 + row;
                size_t base = ((size_t)t * B_DIM + b) * E_DIM + h * 64;
                #pragma unroll
                for (int jd = 0; jd < 4; ++jd) {
                    float v = (o[set][jd][r] + oshare[qhalf][row * 68 + 16 * jd + fr]) * inv;
                    short hs = f2bf(v);
                    short ls = f2bf(v - bf2f(hs));
                    ctxh[base + 16 * jd + fr] = hs;
                    ctxl[base + 16 * jd + fr] = ls;
                }
            }
    }
}

// ---------------------------------------------------------------------------
extern "C" void kernel_launch(void* const* d_in, const int* in_sizes, int n_in,
                              void* d_out, int out_size, void* d_ws, size_t ws_size,
                              hipStream_t stream)
{
    const float* query = (const float*)d_in[0];
    const float* w_in  = (const float*)d_in[1];
    const float* b_in  = (const float*)d_in[2];
    const float* w_out = (const float*)d_in[3];
    const float* b_out = (const float*)d_in[4];
    float* out = (float*)d_out;

    char* ws = (char*)d_ws;
    short* qkv  = (short*)(ws);                  // 25.2 MB
    short* qh   = (short*)(ws + 25165824);       // 8.4 MB
    short* wih  = (short*)(ws + 33554432);       // 6.3 MB
    short* wil  = (short*)(ws + 39845888);       // 6.3 MB
    short* woh  = (short*)(ws + 46137344);       // 2.1 MB
    short* wol  = (short*)(ws + 48234496);       // 2.1 MB
    short* vtp  = (short*)(ws + 50331648);       // 8.4 MB  V^T [bh][d][t]
    short* kp   = (short*)(ws + 58720256);       // 8.4 MB  K frag-order
    short* ctxh = (short*)(ws + 25165824);       // alias qh  (dead after in_proj)
    short* ctxl = (short*)(ws + 33554432);       // alias wih (dead after in_proj)

    const int M = T_DIM * B_DIM;  // 4096

    int nq4  = (M * E_DIM) / 4;
    int nwi4 = (3 * E_DIM * E_DIM) / 4;
    int nwo4 = (E_DIM * E_DIM) / 4;
    split_all_kernel<<<(nq4 + nwi4 + nwo4) / 256, 256, 0, stream>>>(
        query, w_in, w_out, qh, wih, wil, woh, wol, nq4, nwi4, nwo4);

    // in_proj: qkv_bf16 = q @ w_in^T + b_in (w-split, 2 MFMA), q-cols pre-scaled
    gemm_in<<<dim3(3 * E_DIM / 128, M / 128), 256, 0, stream>>>(
        qh, wih, wil, b_in, qkv, M, 3 * E_DIM, E_DIM);

    // one-shot repacks: V -> [bh][d][t], K -> fragment order
    repack_vt<<<dim3(T_DIM / 64, 32), 256, 0, stream>>>(qkv, vtp);
    repack_kf<<<dim3(T_DIM / 64, 32), 256, 0, stream>>>(qkv, kp);

    // attention: 1024 blocks x 256 threads (4 waves: 2 q-halves x 2 key-halves)
    attn_mfma<<<dim3(1024), 256, 0, stream>>>(qkv, kp, vtp, ctxh, ctxl);

    // out_proj: 64x128 tiles -> 512 blocks, full split, 3 MFMA
    gemm_out<<<dim3(E_DIM / 128, M / 64), 256, 0, stream>>>(
        ctxh, ctxl, woh, wol, b_out, out, M, E_DIM, E_DIM);
}

// Round 3
// 223.752 us; speedup vs baseline: 1.9484x; 1.1487x over previous
//
#include <hip/hip_runtime.h>
#include <hip/hip_bf16.h>
#include <math.h>

// Problem constants: T=2048, B=2, E=1024, H=16, d=64
constexpr int T_DIM = 2048;
constexpr int B_DIM = 2;
constexpr int E_DIM = 1024;
// Q pre-scale folded into in_proj epilogue: d^-0.5 * log2(e); attention then
// computes p = exp2(s_scaled) = exp(s_orig * d^-0.5).
constexpr float QK_SCALE = 0.18033688011112042f;

#if __has_builtin(__builtin_amdgcn_exp2f)
#define EXP2F(x) __builtin_amdgcn_exp2f(x)
#else
#define EXP2F(x) exp2f(x)
#endif

typedef __attribute__((ext_vector_type(8))) short short8;   // 8 x bf16 (4 VGPRs)
typedef __attribute__((ext_vector_type(4))) float f32x4;    // MFMA C/D frag

__device__ inline short f2bf(float x) {
    union { __hip_bfloat16 b; short s; } u;
    u.b = __float2bfloat16(x);
    return u.s;
}
__device__ inline float bf2f(short s) {
    union { __hip_bfloat16 b; short s; } u;
    u.s = s;
    return __bfloat162float(u.b);
}

// pack two positive f32 to bf16 pair (lo in low half), RNE-ties-away.
__device__ inline int pack_bf16(float hi, float lo) {
    union { float f; unsigned u; } a, b;
    a.f = hi; b.f = lo;
    return (int)__builtin_amdgcn_perm(a.u + 0x8000u, b.u + 0x8000u, 0x07060302u);
}

__device__ inline void gl2lds16(const void* g, void* l) {
    __builtin_amdgcn_global_load_lds(
        (const __attribute__((address_space(1))) unsigned int*)g,
        (__attribute__((address_space(3))) unsigned int*)l, 16, 0, 0);
}

__device__ inline f32x4 mfma_bf16(short8 a, short8 b, f32x4 c) {
    return __builtin_amdgcn_mfma_f32_16x16x32_bf16(a, b, c, 0, 0, 0);
}

// ---------------------------------------------------------------------------
// Fused split: query (hi only), w_in (hi+lo), w_out (hi+lo). One launch.
// ---------------------------------------------------------------------------
__global__ __launch_bounds__(256)
void split_all_kernel(const float* __restrict__ query,
                      const float* __restrict__ w_in,
                      const float* __restrict__ w_out,
                      short* __restrict__ qh,
                      short* __restrict__ wih, short* __restrict__ wil,
                      short* __restrict__ woh, short* __restrict__ wol,
                      int nq4, int nwi4, int nwo4)
{
    int i = blockIdx.x * 256 + threadIdx.x;
    const float* src; short* dh; short* dl; int k; int do_lo;
    if (i < nq4) { src = query; dh = qh; dl = nullptr; k = i; do_lo = 0; }
    else if (i < nq4 + nwi4) { src = w_in; dh = wih; dl = wil; k = i - nq4; do_lo = 1; }
    else { src = w_out; dh = woh; dl = wol; k = i - nq4 - nwi4; do_lo = 1; }
    float4 v = ((const float4*)src)[k];
    short h0 = f2bf(v.x), h1 = f2bf(v.y), h2 = f2bf(v.z), h3 = f2bf(v.w);
    ((short4*)dh)[k] = make_short4(h0, h1, h2, h3);
    if (do_lo) {
        short l0 = f2bf(v.x - bf2f(h0));
        short l1 = f2bf(v.y - bf2f(h1));
        short l2 = f2bf(v.z - bf2f(h2));
        short l3 = f2bf(v.w - bf2f(h3));
        ((short4*)dl)[k] = make_short4(l0, l1, l2, l3);
    }
}

// ---------------------------------------------------------------------------
// 128x128-tile GEMM (in_proj): C = A @ W^T + bias, 2-MFMA w-split, bf16 out,
// q-columns pre-scaled by QK_SCALE.  (verified r2-r8)
// ---------------------------------------------------------------------------
__global__ __launch_bounds__(256)
void gemm_in(const short* __restrict__ Ah,
             const short* __restrict__ Wh, const short* __restrict__ Wl,
             const float* __restrict__ bias, short* __restrict__ Cout,
             int M, int N, int K)
{
    __shared__ __align__(16) short AsH[128 * 32];
    __shared__ __align__(16) short WsH[128 * 32];
    __shared__ __align__(16) short WsL[128 * 32];

    const int tid  = threadIdx.x;
    const int lane = tid & 63;
    const int wave = tid >> 6;
    const int rm = (wave >> 1) * 64;
    const int cn = (wave & 1) * 64;
    const int m0 = blockIdx.y * 128;
    const int n0 = blockIdx.x * 128;

    const int srow0 = wave * 32 + (lane >> 2);
    const int srow1 = srow0 + 16;
    const int p4 = lane & 3;
    const int kc0 = p4 ^ ((srow0 >> 1) & 3);
    const int kc1 = p4 ^ ((srow1 >> 1) & 3);

    short* ldsA0 = &AsH[(wave * 32) * 32];
    short* ldsA1 = &AsH[(wave * 32 + 16) * 32];
    short* ldsW0 = &WsH[(wave * 32) * 32];
    short* ldsW1 = &WsH[(wave * 32 + 16) * 32];
    short* ldsWl0 = &WsL[(wave * 32) * 32];
    short* ldsWl1 = &WsL[(wave * 32 + 16) * 32];

    const size_t ga0 = (size_t)(m0 + srow0) * K + kc0 * 8;
    const size_t ga1 = (size_t)(m0 + srow1) * K + kc1 * 8;
    const size_t gw0 = (size_t)(n0 + srow0) * K + kc0 * 8;
    const size_t gw1 = (size_t)(n0 + srow1) * K + kc1 * 8;

    const f32x4 zero = {0.f, 0.f, 0.f, 0.f};
    f32x4 acc[4][4];
    #pragma unroll
    for (int i = 0; i < 4; ++i)
        #pragma unroll
        for (int j = 0; j < 4; ++j) acc[i][j] = zero;

    const int fr = lane & 15;
    const int qc = lane >> 4;

    for (int k0 = 0; k0 < K; k0 += 32) {
        if (k0) __syncthreads();
        gl2lds16(Ah + ga0 + k0, ldsA0);
        gl2lds16(Ah + ga1 + k0, ldsA1);
        gl2lds16(Wh + gw0 + k0, ldsW0);
        gl2lds16(Wh + gw1 + k0, ldsW1);
        gl2lds16(Wl + gw0 + k0, ldsWl0);
        gl2lds16(Wl + gw1 + k0, ldsWl1);
        __syncthreads();

        short8 ahf[4], bhf[4], blf[4];
        #pragma unroll
        for (int i = 0; i < 4; ++i) {
            int r = rm + 16 * i + fr;
            int slot = qc ^ ((r >> 1) & 3);
            ahf[i] = *(const short8*)&AsH[r * 32 + slot * 8];
        }
        #pragma unroll
        for (int j = 0; j < 4; ++j) {
            int r = cn + 16 * j + fr;
            int slot = qc ^ ((r >> 1) & 3);
            bhf[j] = *(const short8*)&WsH[r * 32 + slot * 8];
            blf[j] = *(const short8*)&WsL[r * 32 + slot * 8];
        }
        #pragma unroll
        for (int i = 0; i < 4; ++i)
            #pragma unroll
            for (int j = 0; j < 4; ++j) {
                acc[i][j] = mfma_bf16(ahf[i], bhf[j], acc[i][j]);
                acc[i][j] = mfma_bf16(ahf[i], blf[j], acc[i][j]);
            }
    }

    const int g = lane >> 4;
    #pragma unroll
    for (int j = 0; j < 4; ++j) {
        int col = n0 + cn + 16 * j + fr;
        float bj = bias[col];
        float cs = (((col >> 6) % 3) == 0) ? QK_SCALE : 1.0f;
        #pragma unroll
        for (int i = 0; i < 4; ++i)
            #pragma unroll
            for (int r = 0; r < 4; ++r) {
                int row = m0 + rm + 16 * i + g * 4 + r;
                Cout[(size_t)row * N + col] = f2bf((acc[i][j][r] + bj) * cs);
            }
    }
}

// ---------------------------------------------------------------------------
// 64x128-tile GEMM (out_proj): 3-MFMA full split, fp32 out. 512 blocks.
// (verified r7/r8)
// ---------------------------------------------------------------------------
__global__ __launch_bounds__(256)
void gemm_out(const short* __restrict__ Ah, const short* __restrict__ Al,
              const short* __restrict__ Wh, const short* __restrict__ Wl,
              const float* __restrict__ bias, float* __restrict__ Cout,
              int M, int N, int K)
{
    __shared__ __align__(16) short AsH[64 * 32];
    __shared__ __align__(16) short AsL[64 * 32];
    __shared__ __align__(16) short WsH[128 * 32];
    __shared__ __align__(16) short WsL[128 * 32];

    const int tid  = threadIdx.x;
    const int lane = tid & 63;
    const int wave = tid >> 6;
    const int m0 = blockIdx.y * 64;
    const int n0 = blockIdx.x * 128;

    const int arow = wave * 16 + (lane >> 2);
    const int akc = (lane & 3) ^ ((arow >> 1) & 3);
    const size_t gaA = (size_t)(m0 + arow) * K + akc * 8;
    const int wrow0 = wave * 32 + (lane >> 2);
    const int wrow1 = wrow0 + 16;
    const int wkc0 = (lane & 3) ^ ((wrow0 >> 1) & 3);
    const int wkc1 = (lane & 3) ^ ((wrow1 >> 1) & 3);
    const size_t gw0 = (size_t)(n0 + wrow0) * K + wkc0 * 8;
    const size_t gw1 = (size_t)(n0 + wrow1) * K + wkc1 * 8;

    short* ldsAh = &AsH[wave * 512];
    short* ldsAl = &AsL[wave * 512];
    short* ldsW0 = &WsH[(wave * 2) * 512];
    short* ldsW1 = &WsH[(wave * 2 + 1) * 512];
    short* ldsWl0 = &WsL[(wave * 2) * 512];
    short* ldsWl1 = &WsL[(wave * 2 + 1) * 512];

    const f32x4 zero = {0.f, 0.f, 0.f, 0.f};
    f32x4 acc[4][2];
    #pragma unroll
    for (int i = 0; i < 4; ++i) { acc[i][0] = zero; acc[i][1] = zero; }

    const int fr = lane & 15;
    const int g = lane >> 4;

    for (int k0 = 0; k0 < K; k0 += 32) {
        if (k0) __syncthreads();
        gl2lds16(Ah + gaA + k0, ldsAh);
        gl2lds16(Al + gaA + k0, ldsAl);
        gl2lds16(Wh + gw0 + k0, ldsW0);
        gl2lds16(Wh + gw1 + k0, ldsW1);
        gl2lds16(Wl + gw0 + k0, ldsWl0);
        gl2lds16(Wl + gw1 + k0, ldsWl1);
        __syncthreads();

        short8 ahf[4], alf[4], bhf[2], blf[2];
        #pragma unroll
        for (int i = 0; i < 4; ++i) {
            int r = 16 * i + fr;
            int slot = g ^ ((r >> 1) & 3);
            ahf[i] = *(const short8*)&AsH[r * 32 + slot * 8];
            alf[i] = *(const short8*)&AsL[r * 32 + slot * 8];
        }
        #pragma unroll
        for (int j = 0; j < 2; ++j) {
            int r = wave * 32 + 16 * j + fr;
            int slot = g ^ ((r >> 1) & 3);
            bhf[j] = *(const short8*)&WsH[r * 32 + slot * 8];
            blf[j] = *(const short8*)&WsL[r * 32 + slot * 8];
        }
        #pragma unroll
        for (int i = 0; i < 4; ++i)
            #pragma unroll
            for (int j = 0; j < 2; ++j) {
                acc[i][j] = mfma_bf16(ahf[i], bhf[j], acc[i][j]);
                acc[i][j] = mfma_bf16(ahf[i], blf[j], acc[i][j]);
                acc[i][j] = mfma_bf16(alf[i], bhf[j], acc[i][j]);
            }
    }

    #pragma unroll
    for (int j = 0; j < 2; ++j) {
        int col = n0 + wave * 32 + 16 * j + fr;
        float bj = bias[col];
        #pragma unroll
        for (int i = 0; i < 4; ++i)
            #pragma unroll
            for (int r = 0; r < 4; ++r) {
                int row = m0 + 16 * i + g * 4 + r;
                Cout[(size_t)row * N + col] = acc[i][j][r] + bj;
            }
    }
}

// ---------------------------------------------------------------------------
// One-shot V repack into PV MFMA-fragment order (mirrors repack_kf):
// qkv V [t][b][h*192+128+d] -> vtp2 [bh][tile][w*64+lane][8], where
// w = 2*jd+half, lane = (g<<4)|fr holds V^T[16*jd+fr][tile*64+half*32+g*8+i].
// This makes the attn V LDS read the same consecutive-16B pattern as K.
// ---------------------------------------------------------------------------
__global__ __launch_bounds__(256)
void repack_vf(const short* __restrict__ qkv, short* __restrict__ vtp)
{
    __shared__ __align__(16) short Vl[64 * 72];   // [d][t_local], pad 72

    const int tid = threadIdx.x;
    const int t0 = blockIdx.x * 64;
    const int bh = blockIdx.y;
    const int b = bh >> 4, h = bh & 15;
    const int wv = tid >> 6;       // d-range wv*16 .. +15
    const int m  = tid & 63;       // t_local

    const short* src = qkv + ((size_t)(t0 + m) * 2 + b) * 3072 + h * 192 + 128;
    short8 v0 = *(const short8*)(src + (2 * wv) * 8);
    short8 v1 = *(const short8*)(src + (2 * wv + 1) * 8);
    #pragma unroll
    for (int j = 0; j < 8; ++j) {
        Vl[(wv * 16 + j) * 72 + m]     = v0[j];
        Vl[(wv * 16 + 8 + j) * 72 + m] = v1[j];
    }
    __syncthreads();

    short* dst = vtp + (size_t)bh * 131072 + (size_t)blockIdx.x * 4096;
    #pragma unroll
    for (int rr = 0; rr < 2; ++rr) {
        int c = tid + 256 * rr;
        int w = c >> 6, l = c & 63;
        int jd = w >> 1, half = w & 1;
        int g = l >> 4, fr = l & 15;
        uint4 v = *(const uint4*)&Vl[(16 * jd + fr) * 72 + half * 32 + g * 8];
        *(uint4*)(dst + c * 8) = v;
    }
}

// ---------------------------------------------------------------------------
// One-shot K repack into MFMA-fragment order with key permutation baked in.
// (verified r8)
// ---------------------------------------------------------------------------
__global__ __launch_bounds__(256)
void repack_kf(const short* __restrict__ qkv, short* __restrict__ kp)
{
    __shared__ __align__(16) short Kl[64 * 72];

    const int tid = threadIdx.x;
    const int t0 = blockIdx.x * 64;
    const int bh = blockIdx.y;
    const int b = bh >> 4, h = bh & 15;

    #pragma unroll
    for (int rr = 0; rr < 2; ++rr) {
        int c = tid + 256 * rr;
        int m = c >> 3, c8 = c & 7;
        *(uint4*)&Kl[m * 72 + c8 * 8] =
            *(const uint4*)(qkv + ((size_t)(t0 + m) * 2 + b) * 3072 + h * 192 + 64 + c8 * 8);
    }
    __syncthreads();

    short* dst = kp + (size_t)bh * 131072 + (size_t)blockIdx.x * 4096;
    #pragma unroll
    for (int rr = 0; rr < 2; ++rr) {
        int c = tid + 256 * rr;
        int f = c >> 6;
        int l = c & 63;
        int s = f >> 1, hh = f & 1;
        int g = l >> 4, fr = l & 15;
        int R = 16 * s + fr;
        int kk = (R & 32) | ((R & 12) << 1) | ((R & 16) >> 2) | (R & 3);
        uint4 v = *(const uint4*)&Kl[kk * 72 + hh * 32 + g * 8];
        *(uint4*)(dst + c * 8) = v;
    }
}

// ---------------------------------------------------------------------------
// Flash attention v12 — LDS-shared K/V, registers freed.
// r10 post-mortem: register K/V double-buffer = 128 VGPRs/wave -> total
// ~228/wave (108 arch + ~120 AGPR) -> hard 2 waves/SIMD; occupancy lever
// dead while staging stays in registers. r11: block = 4 waves x 32 q-rows
// (128 q-rows) scanning all 2048 keys; K/V tiles staged to a 32 KB LDS
// double-buffer via global_load_lds, shared by all 4 waves (4x less L2
// traffic: 1 GB -> 256 MB) and read just-in-time (consecutive-16B
// ds_read_b128, same frag order for K and V via repack_vf). T3 minimal
// pipeline: stage(it+1) issued right after the barrier, in flight during
// compute(it), drained by next barrier's vmcnt(0). Per-wave regs ~120
// total -> no spill under (256,2).
// ---------------------------------------------------------------------------
__global__ __launch_bounds__(256, 2)
void attn_mfma(const short* __restrict__ qkv, const short* __restrict__ kp,
               const short* __restrict__ vtp,
               short* __restrict__ ctxh, short* __restrict__ ctxl)
{
    __shared__ __align__(16) short ldsK[2][4096];   // 16 KB
    __shared__ __align__(16) short ldsV[2][4096];   // 16 KB

    const int tid  = threadIdx.x;
    const int lane = tid & 63;
    const int wave = tid >> 6;      // 0..3 -> q-rows [wave*32, +32)
    const int fr = lane & 15;
    const int g  = lane >> 4;

    // 512 blocks = 8 XCD-groups x 4 bh x 16 q-blocks(128 rows)
    const int id = blockIdx.x;
    const int x = id & 7, y = id >> 3;
    const int bh = x * 4 + (y & 3);
    const int q0 = (y >> 2) * 128;
    const int b = bh >> 4, h = bh & 15;

    // ---- Q fragments: 2 sets of 16 rows (pre-scaled by QK_SCALE) ----
    short8 aq[2][2];
    #pragma unroll
    for (int set = 0; set < 2; ++set) {
        const short* qrow = qkv +
            ((size_t)(q0 + wave * 32 + set * 16 + fr) * 2 + b) * 3072 + h * 192;
        aq[set][0] = *(const short8*)(qrow + g * 8);
        aq[set][1] = *(const short8*)(qrow + 32 + g * 8);
    }

    const short* kt = kp  + (size_t)bh * 131072;
    const short* vt = vtp + (size_t)bh * 131072;

    short8 ONES;
    #pragma unroll
    for (int i = 0; i < 8; ++i) ONES[i] = (short)0x3F80;  // bf16 1.0

    const f32x4 zero = {0.f, 0.f, 0.f, 0.f};
    f32x4 o[2][4];
    #pragma unroll
    for (int set = 0; set < 2; ++set)
        #pragma unroll
        for (int jd = 0; jd < 4; ++jd) o[set][jd] = zero;
    f32x4 lacc[2] = {zero, zero};

    // stage one 64-key tile (K 8KB + V 8KB) into LDS buffer `sel`
    auto stage = [&](int it, int sel) {
        const short* ks = kt + it * 4096 + wave * 1024 + lane * 8;
        const short* vs = vt + it * 4096 + wave * 1024 + lane * 8;
        gl2lds16(ks,       &ldsK[sel][wave * 1024]);
        gl2lds16(ks + 512, &ldsK[sel][wave * 1024 + 512]);
        gl2lds16(vs,       &ldsV[sel][wave * 1024]);
        gl2lds16(vs + 512, &ldsV[sel][wave * 1024 + 512]);
    };

    stage(0, 0);
    #pragma unroll 2
    for (int it = 0; it < 32; ++it) {
        const int cur = it & 1;
        __syncthreads();                 // vmcnt(0) drain: stage(it) complete;
                                         // all waves done reading buf cur^1
        if (it + 1 < 32) stage(it + 1, cur ^ 1);

        // ---- QK^T + exp2 -> bf16 P fragments ----
        int afw[2][2][4];
        #pragma unroll
        for (int s = 0; s < 4; ++s) {
            short8 k0 = *(const short8*)&ldsK[cur][(2 * s) * 512 + lane * 8];
            short8 k1 = *(const short8*)&ldsK[cur][(2 * s + 1) * 512 + lane * 8];
            #pragma unroll
            for (int set = 0; set < 2; ++set) {
                f32x4 a = zero;
                a = mfma_bf16(k0, aq[set][0], a);
                a = mfma_bf16(k1, aq[set][1], a);
                float e0 = EXP2F(a[0]), e1 = EXP2F(a[1]);
                float e2 = EXP2F(a[2]), e3 = EXP2F(a[3]);
                afw[set][s >> 1][(s & 1) * 2]     = pack_bf16(e1, e0);
                afw[set][s >> 1][(s & 1) * 2 + 1] = pack_bf16(e3, e2);
            }
        }
        union { int w[4]; short8 v; } A[2][2];
        #pragma unroll
        for (int set = 0; set < 2; ++set)
            #pragma unroll
            for (int hh = 0; hh < 2; ++hh)
                #pragma unroll
                for (int w = 0; w < 4; ++w) A[set][hh].w[w] = afw[set][hh][w];

        #pragma unroll
        for (int set = 0; set < 2; ++set) {
            lacc[set] = mfma_bf16(A[set][0].v, ONES, lacc[set]);
            lacc[set] = mfma_bf16(A[set][1].v, ONES, lacc[set]);
        }

        // ---- PV: V frags read once, used by both q-sets ----
        #pragma unroll
        for (int jd = 0; jd < 4; ++jd) {
            short8 v0 = *(const short8*)&ldsV[cur][(2 * jd) * 512 + lane * 8];
            short8 v1 = *(const short8*)&ldsV[cur][(2 * jd + 1) * 512 + lane * 8];
            #pragma unroll
            for (int set = 0; set < 2; ++set) {
                o[set][jd] = mfma_bf16(A[set][0].v, v0, o[set][jd]);
                o[set][jd] = mfma_bf16(A[set][1].v, v1, o[set][jd]);
            }
        }
    }

    // ---- epilogue: normalize (lacc C-layout matches o), split, store ----
    #pragma unroll
    for (int set = 0; set < 2; ++set)
        #pragma unroll
        for (int r = 0; r < 4; ++r) {
            float inv = 1.f / lacc[set][r];
            int t = q0 + wave * 32 + set * 16 + 4 * g + r;
            size_t base = ((size_t)t * B_DIM + b) * E_DIM + h * 64;
            #pragma unroll
            for (int jd = 0; jd < 4; ++jd) {
                float v = o[set][jd][r] * inv;
                short hs = f2bf(v);
                short ls = f2bf(v - bf2f(hs));
                ctxh[base + 16 * jd + fr] = hs;
                ctxl[base + 16 * jd + fr] = ls;
            }
        }
}

// ---------------------------------------------------------------------------
extern "C" void kernel_launch(void* const* d_in, const int* in_sizes, int n_in,
                              void* d_out, int out_size, void* d_ws, size_t ws_size,
                              hipStream_t stream)
{
    const float* query = (const float*)d_in[0];
    const float* w_in  = (const float*)d_in[1];
    const float* b_in  = (const float*)d_in[2];
    const float* w_out = (const float*)d_in[3];
    const float* b_out = (const float*)d_in[4];
    float* out = (float*)d_out;

    char* ws = (char*)d_ws;
    short* qkv  = (short*)(ws);                  // 25.2 MB
    short* qh   = (short*)(ws + 25165824);       // 8.4 MB
    short* wih  = (short*)(ws + 33554432);       // 6.3 MB
    short* wil  = (short*)(ws + 39845888);       // 6.3 MB
    short* woh  = (short*)(ws + 46137344);       // 2.1 MB
    short* wol  = (short*)(ws + 48234496);       // 2.1 MB
    short* vtp  = (short*)(ws + 50331648);       // 8.4 MB  V frag-order
    short* kp   = (short*)(ws + 58720256);       // 8.4 MB  K frag-order
    short* ctxh = (short*)(ws + 25165824);       // alias qh  (dead after in_proj)
    short* ctxl = (short*)(ws + 33554432);       // alias wih (dead after in_proj)

    const int M = T_DIM * B_DIM;  // 4096

    int nq4  = (M * E_DIM) / 4;
    int nwi4 = (3 * E_DIM * E_DIM) / 4;
    int nwo4 = (E_DIM * E_DIM) / 4;
    split_all_kernel<<<(nq4 + nwi4 + nwo4) / 256, 256, 0, stream>>>(
        query, w_in, w_out, qh, wih, wil, woh, wol, nq4, nwi4, nwo4);

    // in_proj: qkv_bf16 = q @ w_in^T + b_in (w-split, 2 MFMA), q-cols pre-scaled
    gemm_in<<<dim3(3 * E_DIM / 128, M / 128), 256, 0, stream>>>(
        qh, wih, wil, b_in, qkv, M, 3 * E_DIM, E_DIM);

    // one-shot repacks: V -> PV frag order, K -> QK frag order
    repack_vf<<<dim3(T_DIM / 64, 32), 256, 0, stream>>>(qkv, vtp);
    repack_kf<<<dim3(T_DIM / 64, 32), 256, 0, stream>>>(qkv, kp);

    // attention: 512 blocks x 256 threads (4 waves x 32 q-rows, LDS K/V dbuf)
    attn_mfma<<<dim3(512), 256, 0, stream>>>(qkv, kp, vtp, ctxh, ctxl);

    // out_proj: 64x128 tiles -> 512 blocks, full split, 3 MFMA
    gemm_out<<<dim3(E_DIM / 128, M / 64), 256, 0, stream>>>(
        ctxh, ctxl, woh, wol, b_out, out, M, E_DIM, E_DIM);
}

// Round 4
// 215.789 us; speedup vs baseline: 2.0203x; 1.0369x over previous
//
#include <hip/hip_runtime.h>
#include <hip/hip_bf16.h>
#include <math.h>

// Problem constants: T=2048, B=2, E=1024, H=16, d=64
constexpr int T_DIM = 2048;
constexpr int B_DIM = 2;
constexpr int E_DIM = 1024;
// Q pre-scale folded into in_proj epilogue: d^-0.5 * log2(e); attention then
// computes p = exp2(s_scaled) = exp(s_orig * d^-0.5).
constexpr float QK_SCALE = 0.18033688011112042f;

#if __has_builtin(__builtin_amdgcn_exp2f)
#define EXP2F(x) __builtin_amdgcn_exp2f(x)
#else
#define EXP2F(x) exp2f(x)
#endif

typedef __attribute__((ext_vector_type(8))) short short8;   // 8 x bf16 (4 VGPRs)
typedef __attribute__((ext_vector_type(4))) float f32x4;    // MFMA C/D frag

__device__ inline short f2bf(float x) {
    union { __hip_bfloat16 b; short s; } u;
    u.b = __float2bfloat16(x);
    return u.s;
}
__device__ inline float bf2f(short s) {
    union { __hip_bfloat16 b; short s; } u;
    u.s = s;
    return __bfloat162float(u.b);
}

// pack two positive f32 to bf16 pair (lo in low half), RNE-ties-away.
__device__ inline int pack_bf16(float hi, float lo) {
    union { float f; unsigned u; } a, b;
    a.f = hi; b.f = lo;
    return (int)__builtin_amdgcn_perm(a.u + 0x8000u, b.u + 0x8000u, 0x07060302u);
}

__device__ inline void gl2lds16(const void* g, void* l) {
    __builtin_amdgcn_global_load_lds(
        (const __attribute__((address_space(1))) unsigned int*)g,
        (__attribute__((address_space(3))) unsigned int*)l, 16, 0, 0);
}

__device__ inline f32x4 mfma_bf16(short8 a, short8 b, f32x4 c) {
    return __builtin_amdgcn_mfma_f32_16x16x32_bf16(a, b, c, 0, 0, 0);
}

// ---------------------------------------------------------------------------
// Fused split: query (hi only), w_in (hi+lo), w_out (hi+lo). One launch.
// ---------------------------------------------------------------------------
__global__ __launch_bounds__(256)
void split_all_kernel(const float* __restrict__ query,
                      const float* __restrict__ w_in,
                      const float* __restrict__ w_out,
                      short* __restrict__ qh,
                      short* __restrict__ wih, short* __restrict__ wil,
                      short* __restrict__ woh, short* __restrict__ wol,
                      int nq4, int nwi4, int nwo4)
{
    int i = blockIdx.x * 256 + threadIdx.x;
    const float* src; short* dh; short* dl; int k; int do_lo;
    if (i < nq4) { src = query; dh = qh; dl = nullptr; k = i; do_lo = 0; }
    else if (i < nq4 + nwi4) { src = w_in; dh = wih; dl = wil; k = i - nq4; do_lo = 1; }
    else { src = w_out; dh = woh; dl = wol; k = i - nq4 - nwi4; do_lo = 1; }
    float4 v = ((const float4*)src)[k];
    short h0 = f2bf(v.x), h1 = f2bf(v.y), h2 = f2bf(v.z), h3 = f2bf(v.w);
    ((short4*)dh)[k] = make_short4(h0, h1, h2, h3);
    if (do_lo) {
        short l0 = f2bf(v.x - bf2f(h0));
        short l1 = f2bf(v.y - bf2f(h1));
        short l2 = f2bf(v.z - bf2f(h2));
        short l3 = f2bf(v.w - bf2f(h3));
        ((short4*)dl)[k] = make_short4(l0, l1, l2, l3);
    }
}

// ---------------------------------------------------------------------------
// 128x128-tile GEMM (in_proj) with FUSED repack epilogue (r12):
// C = A @ W^T + bias; Q cols -> qkv (pre-scaled by QK_SCALE),
// K cols -> kp in QK-MFMA frag order (key permutation baked in),
// V cols -> vtp in PV-MFMA frag order. Identical stored values to the
// old gemm_in + repack_kf + repack_vf chain (verified layouts, r8/r11);
// eliminates 2 kernels and ~50 MB of L2 round-trip.
// Layout inverses:
//   K: m=t&63 -> R=(m&32)|((m&24)>>1)|((m&4)<<2)|(m&3); s=R>>4, frk=R&15;
//      d -> hh=d>>5, gk=(d>>3)&3, ii=d&7;
//      off = bh*131072 + (t>>6)*4096 + ((2s+hh)*64+gk*16+frk)*8 + ii
//   V: tl=t&63 -> half=tl>>5, gv=(tl>>3)&3, iv=tl&7; d -> jd=d>>4, frv=d&15;
//      off = bh*131072 + (t>>6)*4096 + ((2jd+half)*64+gv*16+frv)*8 + iv
// Group/head decode is wave-uniform per j (64-aligned boundaries).
// ---------------------------------------------------------------------------
__global__ __launch_bounds__(256)
void gemm_in(const short* __restrict__ Ah,
             const short* __restrict__ Wh, const short* __restrict__ Wl,
             const float* __restrict__ bias,
             short* __restrict__ qkv, short* __restrict__ kp,
             short* __restrict__ vtp,
             int M, int N, int K)
{
    __shared__ __align__(16) short AsH[128 * 32];
    __shared__ __align__(16) short WsH[128 * 32];
    __shared__ __align__(16) short WsL[128 * 32];

    const int tid  = threadIdx.x;
    const int lane = tid & 63;
    const int wave = tid >> 6;
    const int rm = (wave >> 1) * 64;
    const int cn = (wave & 1) * 64;
    const int m0 = blockIdx.y * 128;
    const int n0 = blockIdx.x * 128;

    const int srow0 = wave * 32 + (lane >> 2);
    const int srow1 = srow0 + 16;
    const int p4 = lane & 3;
    const int kc0 = p4 ^ ((srow0 >> 1) & 3);
    const int kc1 = p4 ^ ((srow1 >> 1) & 3);

    short* ldsA0 = &AsH[(wave * 32) * 32];
    short* ldsA1 = &AsH[(wave * 32 + 16) * 32];
    short* ldsW0 = &WsH[(wave * 32) * 32];
    short* ldsW1 = &WsH[(wave * 32 + 16) * 32];
    short* ldsWl0 = &WsL[(wave * 32) * 32];
    short* ldsWl1 = &WsL[(wave * 32 + 16) * 32];

    const size_t ga0 = (size_t)(m0 + srow0) * K + kc0 * 8;
    const size_t ga1 = (size_t)(m0 + srow1) * K + kc1 * 8;
    const size_t gw0 = (size_t)(n0 + srow0) * K + kc0 * 8;
    const size_t gw1 = (size_t)(n0 + srow1) * K + kc1 * 8;

    const f32x4 zero = {0.f, 0.f, 0.f, 0.f};
    f32x4 acc[4][4];
    #pragma unroll
    for (int i = 0; i < 4; ++i)
        #pragma unroll
        for (int j = 0; j < 4; ++j) acc[i][j] = zero;

    const int fr = lane & 15;
    const int qc = lane >> 4;

    for (int k0 = 0; k0 < K; k0 += 32) {
        if (k0) __syncthreads();
        gl2lds16(Ah + ga0 + k0, ldsA0);
        gl2lds16(Ah + ga1 + k0, ldsA1);
        gl2lds16(Wh + gw0 + k0, ldsW0);
        gl2lds16(Wh + gw1 + k0, ldsW1);
        gl2lds16(Wl + gw0 + k0, ldsWl0);
        gl2lds16(Wl + gw1 + k0, ldsWl1);
        __syncthreads();

        short8 ahf[4], bhf[4], blf[4];
        #pragma unroll
        for (int i = 0; i < 4; ++i) {
            int r = rm + 16 * i + fr;
            int slot = qc ^ ((r >> 1) & 3);
            ahf[i] = *(const short8*)&AsH[r * 32 + slot * 8];
        }
        #pragma unroll
        for (int j = 0; j < 4; ++j) {
            int r = cn + 16 * j + fr;
            int slot = qc ^ ((r >> 1) & 3);
            bhf[j] = *(const short8*)&WsH[r * 32 + slot * 8];
            blf[j] = *(const short8*)&WsL[r * 32 + slot * 8];
        }
        #pragma unroll
        for (int i = 0; i < 4; ++i)
            #pragma unroll
            for (int j = 0; j < 4; ++j) {
                acc[i][j] = mfma_bf16(ahf[i], bhf[j], acc[i][j]);
                acc[i][j] = mfma_bf16(ahf[i], blf[j], acc[i][j]);
            }
    }

    const int g = lane >> 4;
    #pragma unroll
    for (int j = 0; j < 4; ++j) {
        const int colu = n0 + cn + 16 * j;     // 64-block aligned + 16j
        const int col  = colu + fr;
        const float bj = bias[col];
        const int c6  = colu >> 6;             // 3h+grp (wave-uniform)
        const int grp = c6 % 3;
        const int h   = c6 / 3;
        const int d   = (colu & 63) + fr;      // within-head coordinate
        if (grp == 0) {
            // Q -> qkv, pre-scaled
            #pragma unroll
            for (int i = 0; i < 4; ++i)
                #pragma unroll
                for (int r = 0; r < 4; ++r) {
                    int row = m0 + rm + 16 * i + g * 4 + r;
                    qkv[(size_t)row * 3072 + col] =
                        f2bf((acc[i][j][r] + bj) * QK_SCALE);
                }
        } else if (grp == 1) {
            // K -> kp in QK frag order
            const int hh = d >> 5, gk = (d >> 3) & 3, ii = d & 7;
            #pragma unroll
            for (int i = 0; i < 4; ++i)
                #pragma unroll
                for (int r = 0; r < 4; ++r) {
                    int row = m0 + rm + 16 * i + g * 4 + r;
                    int t = row >> 1, bb = row & 1;
                    int m = t & 63;
                    int R = (m & 32) | ((m & 24) >> 1) | ((m & 4) << 2) | (m & 3);
                    size_t off = (size_t)(bb * 16 + h) * 131072
                               + (size_t)(t >> 6) * 4096
                               + (size_t)(((2 * (R >> 4) + hh) * 64
                                           + gk * 16 + (R & 15)) * 8 + ii);
                    kp[off] = f2bf(acc[i][j][r] + bj);
                }
        } else {
            // V -> vtp in PV frag order
            const int jd = d >> 4, frv = d & 15;
            #pragma unroll
            for (int i = 0; i < 4; ++i)
                #pragma unroll
                for (int r = 0; r < 4; ++r) {
                    int row = m0 + rm + 16 * i + g * 4 + r;
                    int t = row >> 1, bb = row & 1;
                    int tl = t & 63;
                    size_t off = (size_t)(bb * 16 + h) * 131072
                               + (size_t)(t >> 6) * 4096
                               + (size_t)(((2 * jd + (tl >> 5)) * 64
                                           + ((tl >> 3) & 3) * 16 + frv) * 8
                                          + (tl & 7));
                    vtp[off] = f2bf(acc[i][j][r] + bj);
                }
        }
    }
}

// ---------------------------------------------------------------------------
// 64x128-tile GEMM (out_proj): 3-MFMA full split, fp32 out. 512 blocks.
// (verified r7/r8)
// ---------------------------------------------------------------------------
__global__ __launch_bounds__(256)
void gemm_out(const short* __restrict__ Ah, const short* __restrict__ Al,
              const short* __restrict__ Wh, const short* __restrict__ Wl,
              const float* __restrict__ bias, float* __restrict__ Cout,
              int M, int N, int K)
{
    __shared__ __align__(16) short AsH[64 * 32];
    __shared__ __align__(16) short AsL[64 * 32];
    __shared__ __align__(16) short WsH[128 * 32];
    __shared__ __align__(16) short WsL[128 * 32];

    const int tid  = threadIdx.x;
    const int lane = tid & 63;
    const int wave = tid >> 6;
    const int m0 = blockIdx.y * 64;
    const int n0 = blockIdx.x * 128;

    const int arow = wave * 16 + (lane >> 2);
    const int akc = (lane & 3) ^ ((arow >> 1) & 3);
    const size_t gaA = (size_t)(m0 + arow) * K + akc * 8;
    const int wrow0 = wave * 32 + (lane >> 2);
    const int wrow1 = wrow0 + 16;
    const int wkc0 = (lane & 3) ^ ((wrow0 >> 1) & 3);
    const int wkc1 = (lane & 3) ^ ((wrow1 >> 1) & 3);
    const size_t gw0 = (size_t)(n0 + wrow0) * K + wkc0 * 8;
    const size_t gw1 = (size_t)(n0 + wrow1) * K + wkc1 * 8;

    short* ldsAh = &AsH[wave * 512];
    short* ldsAl = &AsL[wave * 512];
    short* ldsW0 = &WsH[(wave * 2) * 512];
    short* ldsW1 = &WsH[(wave * 2 + 1) * 512];
    short* ldsWl0 = &WsL[(wave * 2) * 512];
    short* ldsWl1 = &WsL[(wave * 2 + 1) * 512];

    const f32x4 zero = {0.f, 0.f, 0.f, 0.f};
    f32x4 acc[4][2];
    #pragma unroll
    for (int i = 0; i < 4; ++i) { acc[i][0] = zero; acc[i][1] = zero; }

    const int fr = lane & 15;
    const int g = lane >> 4;

    for (int k0 = 0; k0 < K; k0 += 32) {
        if (k0) __syncthreads();
        gl2lds16(Ah + gaA + k0, ldsAh);
        gl2lds16(Al + gaA + k0, ldsAl);
        gl2lds16(Wh + gw0 + k0, ldsW0);
        gl2lds16(Wh + gw1 + k0, ldsW1);
        gl2lds16(Wl + gw0 + k0, ldsWl0);
        gl2lds16(Wl + gw1 + k0, ldsWl1);
        __syncthreads();

        short8 ahf[4], alf[4], bhf[2], blf[2];
        #pragma unroll
        for (int i = 0; i < 4; ++i) {
            int r = 16 * i + fr;
            int slot = g ^ ((r >> 1) & 3);
            ahf[i] = *(const short8*)&AsH[r * 32 + slot * 8];
            alf[i] = *(const short8*)&AsL[r * 32 + slot * 8];
        }
        #pragma unroll
        for (int j = 0; j < 2; ++j) {
            int r = wave * 32 + 16 * j + fr;
            int slot = g ^ ((r >> 1) & 3);
            bhf[j] = *(const short8*)&WsH[r * 32 + slot * 8];
            blf[j] = *(const short8*)&WsL[r * 32 + slot * 8];
        }
        #pragma unroll
        for (int i = 0; i < 4; ++i)
            #pragma unroll
            for (int j = 0; j < 2; ++j) {
                acc[i][j] = mfma_bf16(ahf[i], bhf[j], acc[i][j]);
                acc[i][j] = mfma_bf16(ahf[i], blf[j], acc[i][j]);
                acc[i][j] = mfma_bf16(alf[i], bhf[j], acc[i][j]);
            }
    }

    #pragma unroll
    for (int j = 0; j < 2; ++j) {
        int col = n0 + wave * 32 + 16 * j + fr;
        float bj = bias[col];
        #pragma unroll
        for (int i = 0; i < 4; ++i)
            #pragma unroll
            for (int r = 0; r < 4; ++r) {
                int row = m0 + 16 * i + g * 4 + r;
                Cout[(size_t)row * N + col] = acc[i][j][r] + bj;
            }
    }
}

// ---------------------------------------------------------------------------
// Flash attention v12 — LDS-shared K/V, registers freed. (verified r11)
// Block = 4 waves x 32 q-rows (128 q-rows) scanning all 2048 keys; K/V tiles
// staged to a 32 KB LDS double-buffer via global_load_lds, shared by all 4
// waves, read just-in-time (consecutive-16B ds_read_b128; K and V both in
// MFMA frag order, now produced directly by gemm_in's fused epilogue).
// Single barrier per tile: barrier drains stage(it) and protects buf cur^1.
// ---------------------------------------------------------------------------
__global__ __launch_bounds__(256, 2)
void attn_mfma(const short* __restrict__ qkv, const short* __restrict__ kp,
               const short* __restrict__ vtp,
               short* __restrict__ ctxh, short* __restrict__ ctxl)
{
    __shared__ __align__(16) short ldsK[2][4096];   // 16 KB
    __shared__ __align__(16) short ldsV[2][4096];   // 16 KB

    const int tid  = threadIdx.x;
    const int lane = tid & 63;
    const int wave = tid >> 6;      // 0..3 -> q-rows [wave*32, +32)
    const int fr = lane & 15;
    const int g  = lane >> 4;

    // 512 blocks = 8 XCD-groups x 4 bh x 16 q-blocks(128 rows)
    const int id = blockIdx.x;
    const int x = id & 7, y = id >> 3;
    const int bh = x * 4 + (y & 3);
    const int q0 = (y >> 2) * 128;
    const int b = bh >> 4, h = bh & 15;

    // ---- Q fragments: 2 sets of 16 rows (pre-scaled by QK_SCALE) ----
    short8 aq[2][2];
    #pragma unroll
    for (int set = 0; set < 2; ++set) {
        const short* qrow = qkv +
            ((size_t)(q0 + wave * 32 + set * 16 + fr) * 2 + b) * 3072 + h * 192;
        aq[set][0] = *(const short8*)(qrow + g * 8);
        aq[set][1] = *(const short8*)(qrow + 32 + g * 8);
    }

    const short* kt = kp  + (size_t)bh * 131072;
    const short* vt = vtp + (size_t)bh * 131072;

    short8 ONES;
    #pragma unroll
    for (int i = 0; i < 8; ++i) ONES[i] = (short)0x3F80;  // bf16 1.0

    const f32x4 zero = {0.f, 0.f, 0.f, 0.f};
    f32x4 o[2][4];
    #pragma unroll
    for (int set = 0; set < 2; ++set)
        #pragma unroll
        for (int jd = 0; jd < 4; ++jd) o[set][jd] = zero;
    f32x4 lacc[2] = {zero, zero};

    // stage one 64-key tile (K 8KB + V 8KB) into LDS buffer `sel`
    auto stage = [&](int it, int sel) {
        const short* ks = kt + it * 4096 + wave * 1024 + lane * 8;
        const short* vs = vt + it * 4096 + wave * 1024 + lane * 8;
        gl2lds16(ks,       &ldsK[sel][wave * 1024]);
        gl2lds16(ks + 512, &ldsK[sel][wave * 1024 + 512]);
        gl2lds16(vs,       &ldsV[sel][wave * 1024]);
        gl2lds16(vs + 512, &ldsV[sel][wave * 1024 + 512]);
    };

    stage(0, 0);
    #pragma unroll 2
    for (int it = 0; it < 32; ++it) {
        const int cur = it & 1;
        __syncthreads();                 // vmcnt(0) drain: stage(it) complete;
                                         // all waves done reading buf cur^1
        if (it + 1 < 32) stage(it + 1, cur ^ 1);

        // ---- QK^T + exp2 -> bf16 P fragments ----
        int afw[2][2][4];
        #pragma unroll
        for (int s = 0; s < 4; ++s) {
            short8 k0 = *(const short8*)&ldsK[cur][(2 * s) * 512 + lane * 8];
            short8 k1 = *(const short8*)&ldsK[cur][(2 * s + 1) * 512 + lane * 8];
            #pragma unroll
            for (int set = 0; set < 2; ++set) {
                f32x4 a = zero;
                a = mfma_bf16(k0, aq[set][0], a);
                a = mfma_bf16(k1, aq[set][1], a);
                float e0 = EXP2F(a[0]), e1 = EXP2F(a[1]);
                float e2 = EXP2F(a[2]), e3 = EXP2F(a[3]);
                afw[set][s >> 1][(s & 1) * 2]     = pack_bf16(e1, e0);
                afw[set][s >> 1][(s & 1) * 2 + 1] = pack_bf16(e3, e2);
            }
        }
        union { int w[4]; short8 v; } A[2][2];
        #pragma unroll
        for (int set = 0; set < 2; ++set)
            #pragma unroll
            for (int hh = 0; hh < 2; ++hh)
                #pragma unroll
                for (int w = 0; w < 4; ++w) A[set][hh].w[w] = afw[set][hh][w];

        #pragma unroll
        for (int set = 0; set < 2; ++set) {
            lacc[set] = mfma_bf16(A[set][0].v, ONES, lacc[set]);
            lacc[set] = mfma_bf16(A[set][1].v, ONES, lacc[set]);
        }

        // ---- PV: V frags read once, used by both q-sets ----
        #pragma unroll
        for (int jd = 0; jd < 4; ++jd) {
            short8 v0 = *(const short8*)&ldsV[cur][(2 * jd) * 512 + lane * 8];
            short8 v1 = *(const short8*)&ldsV[cur][(2 * jd + 1) * 512 + lane * 8];
            #pragma unroll
            for (int set = 0; set < 2; ++set) {
                o[set][jd] = mfma_bf16(A[set][0].v, v0, o[set][jd]);
                o[set][jd] = mfma_bf16(A[set][1].v, v1, o[set][jd]);
            }
        }
    }

    // ---- epilogue: normalize (lacc C-layout matches o), split, store ----
    #pragma unroll
    for (int set = 0; set < 2; ++set)
        #pragma unroll
        for (int r = 0; r < 4; ++r) {
            float inv = 1.f / lacc[set][r];
            int t = q0 + wave * 32 + set * 16 + 4 * g + r;
            size_t base = ((size_t)t * B_DIM + b) * E_DIM + h * 64;
            #pragma unroll
            for (int jd = 0; jd < 4; ++jd) {
                float v = o[set][jd][r] * inv;
                short hs = f2bf(v);
                short ls = f2bf(v - bf2f(hs));
                ctxh[base + 16 * jd + fr] = hs;
                ctxl[base + 16 * jd + fr] = ls;
            }
        }
}

// ---------------------------------------------------------------------------
extern "C" void kernel_launch(void* const* d_in, const int* in_sizes, int n_in,
                              void* d_out, int out_size, void* d_ws, size_t ws_size,
                              hipStream_t stream)
{
    const float* query = (const float*)d_in[0];
    const float* w_in  = (const float*)d_in[1];
    const float* b_in  = (const float*)d_in[2];
    const float* w_out = (const float*)d_in[3];
    const float* b_out = (const float*)d_in[4];
    float* out = (float*)d_out;

    char* ws = (char*)d_ws;
    short* qkv  = (short*)(ws);                  // 25.2 MB (Q cols live)
    short* qh   = (short*)(ws + 25165824);       // 8.4 MB
    short* wih  = (short*)(ws + 33554432);       // 6.3 MB
    short* wil  = (short*)(ws + 39845888);       // 6.3 MB
    short* woh  = (short*)(ws + 46137344);       // 2.1 MB
    short* wol  = (short*)(ws + 48234496);       // 2.1 MB
    short* vtp  = (short*)(ws + 50331648);       // 8.4 MB  V frag-order
    short* kp   = (short*)(ws + 58720256);       // 8.4 MB  K frag-order
    short* ctxh = (short*)(ws + 25165824);       // alias qh  (dead after in_proj)
    short* ctxl = (short*)(ws + 33554432);       // alias wih (dead after in_proj)

    const int M = T_DIM * B_DIM;  // 4096

    int nq4  = (M * E_DIM) / 4;
    int nwi4 = (3 * E_DIM * E_DIM) / 4;
    int nwo4 = (E_DIM * E_DIM) / 4;
    split_all_kernel<<<(nq4 + nwi4 + nwo4) / 256, 256, 0, stream>>>(
        query, w_in, w_out, qh, wih, wil, woh, wol, nq4, nwi4, nwo4);

    // in_proj + fused repack: Q -> qkv (scaled), K -> kp, V -> vtp
    gemm_in<<<dim3(3 * E_DIM / 128, M / 128), 256, 0, stream>>>(
        qh, wih, wil, b_in, qkv, kp, vtp, M, 3 * E_DIM, E_DIM);

    // attention: 512 blocks x 256 threads (4 waves x 32 q-rows, LDS K/V dbuf)
    attn_mfma<<<dim3(512), 256, 0, stream>>>(qkv, kp, vtp, ctxh, ctxl);

    // out_proj: 64x128 tiles -> 512 blocks, full split, 3 MFMA
    gemm_out<<<dim3(E_DIM / 128, M / 64), 256, 0, stream>>>(
        ctxh, ctxl, woh, wol, b_out, out, M, E_DIM, E_DIM);
}